// Round 7
// baseline (310.602 us; speedup 1.0000x reference)
//
#include <hip/hip_runtime.h>
#include <hip/hip_bf16.h>

// MessagePassing: out[t] += x[s] for each edge (t, s), D=64.
// edge_index: [2, E] int32 (row 0 = targets, row 1 = sources), x: [N, 64] f32.
//
// Coarse bucket sort (512 buckets x ~98 nodes) with LDS-staged partition
// (coalesced pair writes), then per-bucket fused accumulation in LDS f32
// atomics and one coalesced output write per node.
// Round-7 fix: bsum was latency-bound at 8 waves/CU (274us, Occ 18%).
// Now 1024 thr/block (512 blocks x 16 waves = full machine) and the bucket's
// pair words are staged in LDS first, removing the dependent id->row global
// chain: inner loop has a single global round trip (the row gather).

#define D 64
#define NB2 512        // coarse buckets
#define GPB_MAX 128    // max nodes/bucket supported by bsum LDS (N <= 65536)
#define EPB 4096       // edges per block in bhist/part
#define THR 256
#define BS_THR 1024    // bsum block size
#define CHUNK 2048     // pair words staged per chunk in bsum (8KB)

// ---- A: bucket histogram (LDS-staged) ----
__global__ __launch_bounds__(THR) void bhist_kernel(const int* __restrict__ tgt,
                                                    int* __restrict__ bcnt,
                                                    int E, int gpb) {
    __shared__ int h[NB2];
    int t = threadIdx.x;
    for (int i = t; i < NB2; i += THR) h[i] = 0;
    __syncthreads();
    int base = blockIdx.x * EPB;
    #pragma unroll
    for (int k = 0; k < EPB / THR; ++k) {
        int e = base + t + k * THR;
        if (e < E) atomicAdd(&h[(unsigned)tgt[e] / (unsigned)gpb], 1);
    }
    __syncthreads();
    for (int i = t; i < NB2; i += THR) {
        int v = h[i];
        if (v) atomicAdd(&bcnt[i], v);
    }
}

// ---- B: exclusive scan of bcnt[NB2] -> boff[NB2+1], brun = boff ----
__global__ __launch_bounds__(THR) void bscan_kernel(const int* __restrict__ bcnt,
                                                    int* __restrict__ boff,
                                                    int* __restrict__ brun, int E) {
    __shared__ int a[THR];
    int t = threadIdx.x;
    int s0 = bcnt[2 * t], s1 = bcnt[2 * t + 1];
    a[t] = s0 + s1;
    __syncthreads();
    for (int d = 1; d < THR; d <<= 1) {
        int v = (t >= d) ? a[t - d] : 0;
        __syncthreads();
        a[t] += v;
        __syncthreads();
    }
    int ex = t ? a[t - 1] : 0;
    boff[2 * t] = ex;          brun[2 * t] = ex;
    boff[2 * t + 1] = ex + s0; brun[2 * t + 1] = ex + s0;
    if (t == THR - 1) boff[NB2] = E;
}

// ---- C: partition edges into bucket-grouped pairs (LDS-staged flush) ----
// pair word = (local_tgt << 16) | src   (requires N <= 65536)
__global__ __launch_bounds__(THR) void part_kernel(const int* __restrict__ tgt,
                                                   const int* __restrict__ src,
                                                   int* __restrict__ brun,
                                                   unsigned* __restrict__ pairs,
                                                   int E, int gpb) {
    __shared__ int h[NB2];
    __shared__ int coff[NB2];
    __shared__ int crun[NB2];
    __shared__ int gbase[NB2];
    __shared__ unsigned sw[EPB];
    __shared__ unsigned short sb[EPB];
    __shared__ int a[THR];
    int t = threadIdx.x;
    int base = blockIdx.x * EPB;
    for (int i = t; i < NB2; i += THR) h[i] = 0;
    __syncthreads();

    int myb[EPB / THR];
    unsigned myw[EPB / THR];
    #pragma unroll
    for (int k = 0; k < EPB / THR; ++k) {
        int e = base + t + k * THR;
        int bk = -1; unsigned w = 0;
        if (e < E) {
            unsigned tg = (unsigned)tgt[e];
            unsigned s  = (unsigned)src[e];
            bk = (int)(tg / (unsigned)gpb);
            unsigned lt = tg - (unsigned)bk * (unsigned)gpb;
            w = (lt << 16) | s;
            atomicAdd(&h[bk], 1);
        }
        myb[k] = bk; myw[k] = w;
    }
    __syncthreads();

    // exclusive scan of h (2 elems/thread)
    int s0 = h[2 * t], s1 = h[2 * t + 1];
    a[t] = s0 + s1;
    __syncthreads();
    for (int d = 1; d < THR; d <<= 1) {
        int v = (t >= d) ? a[t - d] : 0;
        __syncthreads();
        a[t] += v;
        __syncthreads();
    }
    int ex = t ? a[t - 1] : 0;
    coff[2 * t] = ex;          crun[2 * t] = ex;
    coff[2 * t + 1] = ex + s0; crun[2 * t + 1] = ex + s0;
    __syncthreads();

    // place into staging (bucket-grouped within block)
    #pragma unroll
    for (int k = 0; k < EPB / THR; ++k) {
        if (myb[k] >= 0) {
            int pos = atomicAdd(&crun[myb[k]], 1);
            sw[pos] = myw[k];
            sb[pos] = (unsigned short)myb[k];
        }
    }
    // reserve global space per bucket (h is stable)
    int b0 = t, b1 = t + THR;
    gbase[b0] = h[b0] ? atomicAdd(&brun[b0], h[b0]) : 0;
    gbase[b1] = h[b1] ? atomicAdd(&brun[b1], h[b1]) : 0;
    __syncthreads();

    // flush: consecutive i within a bucket run -> consecutive global dst
    int nitems = a[THR - 1];
    for (int i = t; i < nitems; i += THR) {
        int bk = sb[i];
        pairs[gbase[bk] + (i - coff[bk])] = sw[i];
    }
}

// ---- D: per-bucket accumulate in LDS + coalesced output ----
// 16 waves/block; pair words staged in LDS (id reads become LDS broadcasts);
// each wave keeps 8 row gathers in flight; LDS f32 atomics (2-way bank = free).
__global__ __launch_bounds__(BS_THR) void bsum_kernel(const int* __restrict__ boff,
                                                      const unsigned* __restrict__ pairs,
                                                      const float* __restrict__ x,
                                                      float* __restrict__ out,
                                                      int N, int gpb) {
    __shared__ float acc[GPB_MAX * D];   // 32KB
    __shared__ unsigned sp[CHUNK];       // 8KB
    int b = blockIdx.x;
    int t = threadIdx.x;
    int lo = b * gpb;
    if (lo >= N) return;
    int hi = lo + gpb; if (hi > N) hi = N;
    int nn = hi - lo;
    for (int i = t; i < nn * D; i += BS_THR) acc[i] = 0.f;

    int s = boff[b], e = boff[b + 1];
    int wid = t >> 6;    // 0..15
    int lane = t & 63;
    for (int cbase = s; cbase < e; cbase += CHUNK) {
        int m = e - cbase; if (m > CHUNK) m = CHUNK;
        __syncthreads();   // acc-init done (first iter) / prev chunk consumed
        for (int i = t; i < m; i += BS_THR) sp[i] = pairs[cbase + i];
        __syncthreads();
        for (int jb = wid * 8; jb < m; jb += 16 * 8) {
            unsigned w[8]; float v[8];
            #pragma unroll
            for (int k = 0; k < 8; ++k) {
                int j = jb + k;
                w[k] = sp[(j < m) ? j : 0];
            }
            #pragma unroll
            for (int k = 0; k < 8; ++k)
                v[k] = x[(w[k] & 0xffffu) * D + lane];
            #pragma unroll
            for (int k = 0; k < 8; ++k) {
                if (jb + k < m) {             // wave-uniform predicate
                    atomicAdd(&acc[(w[k] >> 16) * D + lane], v[k]);
                }
            }
        }
    }
    __syncthreads();

    const float4* a4 = (const float4*)acc;
    float4* o4 = (float4*)(out + (size_t)lo * D);
    int n4 = nn * (D / 4);
    for (int i = t; i < n4; i += BS_THR) o4[i] = a4[i];
}

// Fallback: direct atomic scatter-add.
__global__ void mp_scatter_add_kernel(const int* __restrict__ tgt,
                                      const int* __restrict__ src,
                                      const float* __restrict__ x,
                                      float* __restrict__ out,
                                      int E) {
    long long tid = (long long)blockIdx.x * blockDim.x + threadIdx.x;
    int e = (int)(tid >> 6);
    int d = (int)(tid & 63);
    if (e >= E) return;
    atomicAdd(&out[(long long)tgt[e] * D + d], x[(long long)src[e] * D + d]);
}

extern "C" void kernel_launch(void* const* d_in, const int* in_sizes, int n_in,
                              void* d_out, int out_size, void* d_ws, size_t ws_size,
                              hipStream_t stream) {
    const int* edge_index = (const int*)d_in[0];   // [2, E]
    const float* x        = (const float*)d_in[1]; // [N, 64]
    float* out            = (float*)d_out;         // [N, 64]

    int E = in_sizes[0] / 2;
    int N = out_size / D;
    const int* tgt = edge_index;       // edge_index[0]
    const int* src = edge_index + E;   // edge_index[1]

    int gpb = (N + NB2 - 1) / NB2;     // nodes per bucket (98 for N=50000)

    // ws layout (int segments): bcnt[512] | boff[516] | brun[512] | pairs[E]
    size_t need = (size_t)(NB2 + (NB2 + 4) + NB2 + E) * sizeof(int);

    if (N > 65536 || gpb > GPB_MAX || ws_size < need) {
        hipMemsetAsync(d_out, 0, (size_t)out_size * sizeof(float), stream);
        long long total = (long long)E * D;
        long long grid = (total + THR - 1) / THR;
        mp_scatter_add_kernel<<<(dim3)(unsigned)grid, THR, 0, stream>>>(tgt, src, x, out, E);
        return;
    }

    int* bcnt = (int*)d_ws;
    int* boff = bcnt + NB2;
    int* brun = boff + (NB2 + 4);
    unsigned* pairs = (unsigned*)(brun + NB2);

    hipMemsetAsync(bcnt, 0, NB2 * sizeof(int), stream);

    int GE = (E + EPB - 1) / EPB;
    bhist_kernel<<<GE, THR, 0, stream>>>(tgt, bcnt, E, gpb);
    bscan_kernel<<<1, THR, 0, stream>>>(bcnt, boff, brun, E);
    part_kernel<<<GE, THR, 0, stream>>>(tgt, src, brun, pairs, E, gpb);
    bsum_kernel<<<NB2, BS_THR, 0, stream>>>(boff, pairs, x, out, N, gpb);
}

// Round 8
// 63.392 us; speedup vs baseline: 4.8997x; 4.8997x over previous
//
#include <hip/hip_runtime.h>
#include <hip/hip_bf16.h>

// MessagePassing: out[t] += x[s] for each edge (t, s), D=64.
// edge_index: [2, E] int32 (row 0 = targets, row 1 = sources), x: [N, 64] f32.
//
// Coarse bucket sort (512 buckets x ~98 nodes) with LDS-staged partition,
// then per-bucket accumulation.
// Round-8 fix: rounds 6/7 bsum was a 280us wall INVARIANT to occupancy
// (18%->72%, same dur) -> shared-pipe serialization: the per-edge wave64
// LDS f32 atomic RMW. New bsum: counting-sort the bucket's pairs by local
// target in LDS (cheap single-lane int atomics), then REGISTER accumulation
// (wave owns nodes wid+16r, lane=dim, 8-deep gather pipeline), one coalesced
// store per node. Zero f32 atomics anywhere.

#define D 64
#define NB2 512        // coarse buckets
#define GPB_MAX 128    // max nodes/bucket (N <= 65536 also required for u16 packing)
#define EPB 4096       // edges per block in bhist/part
#define THR 256
#define BS_THR 1024    // bsum block size
#define CH 4096        // pairs per sort-chunk in bsum (u16 stage = 8KB)

// ---- A: bucket histogram (LDS-staged) ----
__global__ __launch_bounds__(THR) void bhist_kernel(const int* __restrict__ tgt,
                                                    int* __restrict__ bcnt,
                                                    int E, int gpb) {
    __shared__ int h[NB2];
    int t = threadIdx.x;
    for (int i = t; i < NB2; i += THR) h[i] = 0;
    __syncthreads();
    int base = blockIdx.x * EPB;
    #pragma unroll
    for (int k = 0; k < EPB / THR; ++k) {
        int e = base + t + k * THR;
        if (e < E) atomicAdd(&h[(unsigned)tgt[e] / (unsigned)gpb], 1);
    }
    __syncthreads();
    for (int i = t; i < NB2; i += THR) {
        int v = h[i];
        if (v) atomicAdd(&bcnt[i], v);
    }
}

// ---- B: exclusive scan of bcnt[NB2] -> boff[NB2+1], brun = boff ----
__global__ __launch_bounds__(THR) void bscan_kernel(const int* __restrict__ bcnt,
                                                    int* __restrict__ boff,
                                                    int* __restrict__ brun, int E) {
    __shared__ int a[THR];
    int t = threadIdx.x;
    int s0 = bcnt[2 * t], s1 = bcnt[2 * t + 1];
    a[t] = s0 + s1;
    __syncthreads();
    for (int d = 1; d < THR; d <<= 1) {
        int v = (t >= d) ? a[t - d] : 0;
        __syncthreads();
        a[t] += v;
        __syncthreads();
    }
    int ex = t ? a[t - 1] : 0;
    boff[2 * t] = ex;          brun[2 * t] = ex;
    boff[2 * t + 1] = ex + s0; brun[2 * t + 1] = ex + s0;
    if (t == THR - 1) boff[NB2] = E;
}

// ---- C: partition edges into bucket-grouped pairs (LDS-staged flush) ----
// pair word = (local_tgt << 16) | src   (requires N <= 65536)
__global__ __launch_bounds__(THR) void part_kernel(const int* __restrict__ tgt,
                                                   const int* __restrict__ src,
                                                   int* __restrict__ brun,
                                                   unsigned* __restrict__ pairs,
                                                   int E, int gpb) {
    __shared__ int h[NB2];
    __shared__ int coff[NB2];
    __shared__ int crun[NB2];
    __shared__ int gbase[NB2];
    __shared__ unsigned sw[EPB];
    __shared__ unsigned short sb[EPB];
    __shared__ int a[THR];
    int t = threadIdx.x;
    int base = blockIdx.x * EPB;
    for (int i = t; i < NB2; i += THR) h[i] = 0;
    __syncthreads();

    int myb[EPB / THR];
    unsigned myw[EPB / THR];
    #pragma unroll
    for (int k = 0; k < EPB / THR; ++k) {
        int e = base + t + k * THR;
        int bk = -1; unsigned w = 0;
        if (e < E) {
            unsigned tg = (unsigned)tgt[e];
            unsigned s  = (unsigned)src[e];
            bk = (int)(tg / (unsigned)gpb);
            unsigned lt = tg - (unsigned)bk * (unsigned)gpb;
            w = (lt << 16) | s;
            atomicAdd(&h[bk], 1);
        }
        myb[k] = bk; myw[k] = w;
    }
    __syncthreads();

    // exclusive scan of h (2 elems/thread)
    int s0 = h[2 * t], s1 = h[2 * t + 1];
    a[t] = s0 + s1;
    __syncthreads();
    for (int d = 1; d < THR; d <<= 1) {
        int v = (t >= d) ? a[t - d] : 0;
        __syncthreads();
        a[t] += v;
        __syncthreads();
    }
    int ex = t ? a[t - 1] : 0;
    coff[2 * t] = ex;          crun[2 * t] = ex;
    coff[2 * t + 1] = ex + s0; crun[2 * t + 1] = ex + s0;
    __syncthreads();

    // place into staging (bucket-grouped within block)
    #pragma unroll
    for (int k = 0; k < EPB / THR; ++k) {
        if (myb[k] >= 0) {
            int pos = atomicAdd(&crun[myb[k]], 1);
            sw[pos] = myw[k];
            sb[pos] = (unsigned short)myb[k];
        }
    }
    // reserve global space per bucket (h is stable)
    int b0 = t, b1 = t + THR;
    gbase[b0] = h[b0] ? atomicAdd(&brun[b0], h[b0]) : 0;
    gbase[b1] = h[b1] ? atomicAdd(&brun[b1], h[b1]) : 0;
    __syncthreads();

    // flush: consecutive i within a bucket run -> consecutive global dst
    int nitems = a[THR - 1];
    for (int i = t; i < nitems; i += THR) {
        int bk = sb[i];
        pairs[gbase[bk] + (i - coff[bk])] = sw[i];
    }
}

// ---- D: per-bucket counting sort (LDS) + register accumulate ----
// Wave wid owns nodes wid+16r (r<8, static). Lane = feature dim.
// Per chunk: hist(lt) -> wave-0 shfl scan -> scatter u16 src ids sorted by lt
// -> each wave runs its nodes' contiguous id lists, 8 gathers in flight,
// accumulating in registers. One coalesced 256B store per node at the end.
__global__ __launch_bounds__(BS_THR) void bsum_kernel(const int* __restrict__ boff,
                                                      const unsigned* __restrict__ pairs,
                                                      const float* __restrict__ x,
                                                      float* __restrict__ out,
                                                      int N, int gpb) {
    __shared__ int cnt2[GPB_MAX];
    __shared__ int roff[GPB_MAX + 1];
    __shared__ int wpos[GPB_MAX];
    __shared__ unsigned short ss[CH];
    int b = blockIdx.x;
    int t = threadIdx.x;
    int lo = b * gpb;
    if (lo >= N) return;
    int hi = lo + gpb; if (hi > N) hi = N;
    int nn = hi - lo;
    int wid = t >> 6;
    int lane = t & 63;

    float acc[8];
    #pragma unroll
    for (int r = 0; r < 8; ++r) acc[r] = 0.f;

    int s = boff[b], e = boff[b + 1];
    for (int cb = s; cb < e; cb += CH) {
        int m = e - cb; if (m > CH) m = CH;
        __syncthreads();              // previous chunk fully consumed
        if (t < GPB_MAX) cnt2[t] = 0;
        __syncthreads();
        // histogram of local targets (single-lane int atomics)
        for (int i = t; i < m; i += BS_THR)
            atomicAdd(&cnt2[pairs[cb + i] >> 16], 1);
        __syncthreads();
        // exclusive scan of 128 counters by wave 0 (shfl scan)
        if (wid == 0) {
            int c0 = cnt2[lane], c1 = cnt2[64 + lane];
            int s0c = c0, s1c = c1;
            for (int d2 = 1; d2 < 64; d2 <<= 1) {
                int v = __shfl_up(s0c, d2); if (lane >= d2) s0c += v;
            }
            int tot0 = __shfl(s0c, 63);
            for (int d2 = 1; d2 < 64; d2 <<= 1) {
                int v = __shfl_up(s1c, d2); if (lane >= d2) s1c += v;
            }
            roff[lane] = s0c - c0;        wpos[lane] = s0c - c0;
            roff[64 + lane] = tot0 + s1c - c1;
            wpos[64 + lane] = tot0 + s1c - c1;
            if (lane == 63) roff[GPB_MAX] = tot0 + s1c;
        }
        __syncthreads();
        // scatter src ids into sorted order (u16)
        for (int i = t; i < m; i += BS_THR) {
            unsigned w = pairs[cb + i];
            int pos = atomicAdd(&wpos[w >> 16], 1);
            ss[pos] = (unsigned short)(w & 0xffffu);
        }
        __syncthreads();
        // register accumulation over each owned node's contiguous run
        #pragma unroll
        for (int r = 0; r < 8; ++r) {
            int node = wid + (r << 4);           // wave-uniform
            if (node < nn) {
                int rs = roff[node], re = roff[node + 1];
                float a = acc[r];
                for (int j = rs; j < re; j += 8) {
                    int idv[8]; float vv[8];
                    #pragma unroll
                    for (int k = 0; k < 8; ++k) {
                        int jj = j + k;
                        idv[k] = ss[(jj < re) ? jj : rs];
                    }
                    #pragma unroll
                    for (int k = 0; k < 8; ++k)
                        vv[k] = x[idv[k] * D + lane];
                    #pragma unroll
                    for (int k = 0; k < 8; ++k)
                        if (j + k < re) a += vv[k];
                }
                acc[r] = a;
            }
        }
    }
    // one coalesced store per node (empty buckets/nodes write zeros)
    #pragma unroll
    for (int r = 0; r < 8; ++r) {
        int node = wid + (r << 4);
        if (node < nn) out[(size_t)(lo + node) * D + lane] = acc[r];
    }
}

// Fallback: direct atomic scatter-add.
__global__ void mp_scatter_add_kernel(const int* __restrict__ tgt,
                                      const int* __restrict__ src,
                                      const float* __restrict__ x,
                                      float* __restrict__ out,
                                      int E) {
    long long tid = (long long)blockIdx.x * blockDim.x + threadIdx.x;
    int e = (int)(tid >> 6);
    int d = (int)(tid & 63);
    if (e >= E) return;
    atomicAdd(&out[(long long)tgt[e] * D + d], x[(long long)src[e] * D + d]);
}

extern "C" void kernel_launch(void* const* d_in, const int* in_sizes, int n_in,
                              void* d_out, int out_size, void* d_ws, size_t ws_size,
                              hipStream_t stream) {
    const int* edge_index = (const int*)d_in[0];   // [2, E]
    const float* x        = (const float*)d_in[1]; // [N, 64]
    float* out            = (float*)d_out;         // [N, 64]

    int E = in_sizes[0] / 2;
    int N = out_size / D;
    const int* tgt = edge_index;       // edge_index[0]
    const int* src = edge_index + E;   // edge_index[1]

    int gpb = (N + NB2 - 1) / NB2;     // nodes per bucket (98 for N=50000)

    // ws layout (int segments): bcnt[512] | boff[516] | brun[512] | pairs[E]
    size_t need = (size_t)(NB2 + (NB2 + 4) + NB2 + E) * sizeof(int);

    if (N > 65536 || gpb > GPB_MAX || ws_size < need) {
        hipMemsetAsync(d_out, 0, (size_t)out_size * sizeof(float), stream);
        long long total = (long long)E * D;
        long long grid = (total + THR - 1) / THR;
        mp_scatter_add_kernel<<<(dim3)(unsigned)grid, THR, 0, stream>>>(tgt, src, x, out, E);
        return;
    }

    int* bcnt = (int*)d_ws;
    int* boff = bcnt + NB2;
    int* brun = boff + (NB2 + 4);
    unsigned* pairs = (unsigned*)(brun + NB2);

    hipMemsetAsync(bcnt, 0, NB2 * sizeof(int), stream);

    int GE = (E + EPB - 1) / EPB;
    bhist_kernel<<<GE, THR, 0, stream>>>(tgt, bcnt, E, gpb);
    bscan_kernel<<<1, THR, 0, stream>>>(bcnt, boff, brun, E);
    part_kernel<<<GE, THR, 0, stream>>>(tgt, src, brun, pairs, E, gpb);
    bsum_kernel<<<NB2, BS_THR, 0, stream>>>(boff, pairs, x, out, N, gpb);
}

// Round 9
// 47.529 us; speedup vs baseline: 6.5351x; 1.3338x over previous
//
#include <hip/hip_runtime.h>
#include <hip/hip_bf16.h>

// MessagePassing: out[t] += x[s] for each edge (t, s), D=64.
// edge_index: [2, E] int32 (row 0 = targets, row 1 = sources), x: [N, 64] f32.
//
// Round-9: fixed-capacity bucket regions kill bhist+bscan (2 dispatches + a
// full tgt read); part at 1024 thr/block (16 waves, was 4) hides staging
// latency; bsum stages the bucket's pairs in LDS once (single chunk).
// Overflow (>cap edges/bucket, ~12 sigma) goes to an exact spill list fixed
// by a post-pass global-atomic kernel (normally 0 entries).

#define D 64
#define NB2 512         // coarse buckets
#define GPB_MAX 128     // max nodes/bucket (needs N <= 65536 for u16 packing)
#define CAP 2048        // pair words per bucket region
#define EPB 4096        // edges per part block
#define PTHR 1024       // part threads
#define BTHR 1024       // bsum threads
#define SPILL_MAX 65536

// ---- 0: init bucket cursors + spill count ----
__global__ void init_kernel(int* __restrict__ brun, int* __restrict__ scnt) {
    int t = threadIdx.x;
    if (t < NB2) brun[t] = t * CAP;
    if (t == NB2) scnt[0] = 0;
}

// ---- 1: partition edges into fixed-cap bucket regions (LDS-staged flush) ----
// pair word = (local_tgt << 16) | src   (requires N <= 65536)
__global__ __launch_bounds__(PTHR) void part_kernel(const int* __restrict__ tgt,
                                                    const int* __restrict__ src,
                                                    int* __restrict__ brun,
                                                    unsigned* __restrict__ pairs,
                                                    int* __restrict__ spill,
                                                    int* __restrict__ scnt,
                                                    int E, int gpb) {
    __shared__ int h[NB2];
    __shared__ int coff[NB2];
    __shared__ int crun[NB2];
    __shared__ int gbase[NB2];
    __shared__ int a[NB2];
    __shared__ unsigned sw[EPB];
    __shared__ unsigned short sb[EPB];
    int t = threadIdx.x;
    int base = blockIdx.x * EPB;
    for (int i = t; i < NB2; i += PTHR) h[i] = 0;
    __syncthreads();

    int myb[EPB / PTHR];
    unsigned myw[EPB / PTHR];
    #pragma unroll
    for (int k = 0; k < EPB / PTHR; ++k) {
        int e = base + t + k * PTHR;
        int bk = -1; unsigned w = 0;
        if (e < E) {
            unsigned tg = (unsigned)tgt[e];
            unsigned s  = (unsigned)src[e];
            bk = (int)(tg / (unsigned)gpb);
            unsigned lt = tg - (unsigned)bk * (unsigned)gpb;
            w = (lt << 16) | s;
            atomicAdd(&h[bk], 1);
        }
        myb[k] = bk; myw[k] = w;
    }
    __syncthreads();

    // exclusive scan of h[512] (first 512 threads, Hillis-Steele)
    if (t < NB2) a[t] = h[t];
    __syncthreads();
    for (int d = 1; d < NB2; d <<= 1) {
        int v = 0;
        if (t < NB2 && t >= d) v = a[t - d];
        __syncthreads();
        if (t < NB2) a[t] += v;
        __syncthreads();
    }
    if (t < NB2) {
        int ex = t ? a[t - 1] : 0;
        coff[t] = ex; crun[t] = ex;
    }
    __syncthreads();

    // place into staging (bucket-grouped within block)
    #pragma unroll
    for (int k = 0; k < EPB / PTHR; ++k) {
        if (myb[k] >= 0) {
            int pos = atomicAdd(&crun[myb[k]], 1);
            sw[pos] = myw[k];
            sb[pos] = (unsigned short)myb[k];
        }
    }
    // reserve global space per bucket (h is stable now)
    if (t < NB2) gbase[t] = h[t] ? atomicAdd(&brun[t], h[t]) : 0;
    __syncthreads();

    // flush: consecutive i within a bucket run -> consecutive global dst
    int nitems = a[NB2 - 1];
    for (int i = t; i < nitems; i += PTHR) {
        int bk = sb[i];
        int dst = gbase[bk] + (i - coff[bk]);
        if (dst < (bk + 1) * CAP) {
            pairs[dst] = sw[i];
        } else {
            int sp = atomicAdd(scnt, 1);
            if (sp < SPILL_MAX) {
                unsigned w = sw[i];
                spill[2 * sp]     = bk * gpb + (int)(w >> 16);
                spill[2 * sp + 1] = (int)(w & 0xffffu);
            }
        }
    }
}

// ---- 2: per-bucket counting sort (LDS) + register accumulate ----
// Wave wid owns nodes wid+16r (r<8, static). Lane = feature dim.
__global__ __launch_bounds__(BTHR) void bsum_kernel(const int* __restrict__ brun,
                                                    const unsigned* __restrict__ pairs,
                                                    const float* __restrict__ x,
                                                    float* __restrict__ out,
                                                    int N, int gpb) {
    __shared__ unsigned sp[CAP];         // 8KB: staged pair words
    __shared__ unsigned short ss[CAP];   // 4KB: sorted src ids
    __shared__ int cnt2[GPB_MAX];
    __shared__ int roff[GPB_MAX + 1];
    __shared__ int wpos[GPB_MAX];
    int b = blockIdx.x;
    int t = threadIdx.x;
    int lo = b * gpb;
    if (lo >= N) return;
    int hi = lo + gpb; if (hi > N) hi = N;
    int nn = hi - lo;
    int wid = t >> 6;
    int lane = t & 63;

    int m = brun[b] - b * CAP;
    if (m > CAP) m = CAP;       // excess went to the spill list

    // stage pair words (coalesced), zero counters
    for (int i = t; i < m; i += BTHR) sp[i] = pairs[b * CAP + i];
    if (t < GPB_MAX) cnt2[t] = 0;
    __syncthreads();
    // histogram of local targets (single-lane int atomics, from LDS)
    for (int i = t; i < m; i += BTHR) atomicAdd(&cnt2[sp[i] >> 16], 1);
    __syncthreads();
    // exclusive scan of 128 counters by wave 0 (shfl scan)
    if (wid == 0) {
        int c0 = cnt2[lane], c1 = cnt2[64 + lane];
        int s0c = c0, s1c = c1;
        for (int d2 = 1; d2 < 64; d2 <<= 1) {
            int v = __shfl_up(s0c, d2); if (lane >= d2) s0c += v;
        }
        int tot0 = __shfl(s0c, 63);
        for (int d2 = 1; d2 < 64; d2 <<= 1) {
            int v = __shfl_up(s1c, d2); if (lane >= d2) s1c += v;
        }
        roff[lane] = s0c - c0;        wpos[lane] = s0c - c0;
        roff[64 + lane] = tot0 + s1c - c1;
        wpos[64 + lane] = tot0 + s1c - c1;
        if (lane == 63) roff[GPB_MAX] = tot0 + s1c;
    }
    __syncthreads();
    // scatter src ids into sorted order (u16, LDS->LDS)
    for (int i = t; i < m; i += BTHR) {
        unsigned w = sp[i];
        int pos = atomicAdd(&wpos[w >> 16], 1);
        ss[pos] = (unsigned short)(w & 0xffffu);
    }
    __syncthreads();

    float acc[8];
    #pragma unroll
    for (int r = 0; r < 8; ++r) acc[r] = 0.f;
    // register accumulation over each owned node's contiguous run
    #pragma unroll
    for (int r = 0; r < 8; ++r) {
        int node = wid + (r << 4);           // wave-uniform
        if (node < nn) {
            int rs = roff[node], re = roff[node + 1];
            float a = acc[r];
            for (int j = rs; j < re; j += 8) {
                int idv[8]; float vv[8];
                #pragma unroll
                for (int k = 0; k < 8; ++k) {
                    int jj = j + k;
                    idv[k] = ss[(jj < re) ? jj : rs];
                }
                #pragma unroll
                for (int k = 0; k < 8; ++k)
                    vv[k] = x[idv[k] * D + lane];
                #pragma unroll
                for (int k = 0; k < 8; ++k)
                    if (j + k < re) a += vv[k];
            }
            acc[r] = a;
        }
    }
    // one coalesced store per node (zeros included)
    #pragma unroll
    for (int r = 0; r < 8; ++r) {
        int node = wid + (r << 4);
        if (node < nn) out[(size_t)(lo + node) * D + lane] = acc[r];
    }
}

// ---- 3: exact fixup for spilled edges (normally zero) ----
__global__ void spill_kernel(const int* __restrict__ spill,
                             const int* __restrict__ scnt,
                             const float* __restrict__ x,
                             float* __restrict__ out) {
    int n = scnt[0]; if (n > SPILL_MAX) n = SPILL_MAX;
    int lane = threadIdx.x & 63;
    int wave = (int)((blockIdx.x * blockDim.x + threadIdx.x) >> 6);
    int nw = (int)((gridDim.x * blockDim.x) >> 6);
    for (int i = wave; i < n; i += nw) {
        int tg = spill[2 * i], s = spill[2 * i + 1];
        atomicAdd(&out[(size_t)tg * D + lane], x[(size_t)s * D + lane]);
    }
}

// Fallback: direct atomic scatter-add.
__global__ void mp_scatter_add_kernel(const int* __restrict__ tgt,
                                      const int* __restrict__ src,
                                      const float* __restrict__ x,
                                      float* __restrict__ out,
                                      int E) {
    long long tid = (long long)blockIdx.x * blockDim.x + threadIdx.x;
    int e = (int)(tid >> 6);
    int d = (int)(tid & 63);
    if (e >= E) return;
    atomicAdd(&out[(long long)tgt[e] * D + d], x[(long long)src[e] * D + d]);
}

extern "C" void kernel_launch(void* const* d_in, const int* in_sizes, int n_in,
                              void* d_out, int out_size, void* d_ws, size_t ws_size,
                              hipStream_t stream) {
    const int* edge_index = (const int*)d_in[0];   // [2, E]
    const float* x        = (const float*)d_in[1]; // [N, 64]
    float* out            = (float*)d_out;         // [N, 64]

    int E = in_sizes[0] / 2;
    int N = out_size / D;
    const int* tgt = edge_index;       // edge_index[0]
    const int* src = edge_index + E;   // edge_index[1]

    int gpb = (N + NB2 - 1) / NB2;     // nodes per bucket (98 for N=50000)

    // ws layout (ints): brun[512] | scnt[4] | pairs[512*CAP] | spill[2*SPILL_MAX]
    size_t need = (size_t)(NB2 + 4 + NB2 * CAP + 2 * SPILL_MAX) * sizeof(int);

    if (N > 65536 || gpb > GPB_MAX || ws_size < need) {
        hipMemsetAsync(d_out, 0, (size_t)out_size * sizeof(float), stream);
        long long total = (long long)E * D;
        long long grid = (total + 255) / 256;
        mp_scatter_add_kernel<<<(dim3)(unsigned)grid, 256, 0, stream>>>(tgt, src, x, out, E);
        return;
    }

    int* brun = (int*)d_ws;
    int* scnt = brun + NB2;
    unsigned* pairs = (unsigned*)(scnt + 4);
    int* spill = (int*)(pairs + (size_t)NB2 * CAP);

    init_kernel<<<1, NB2 + 64, 0, stream>>>(brun, scnt);
    int GE = (E + EPB - 1) / EPB;
    part_kernel<<<GE, PTHR, 0, stream>>>(tgt, src, brun, pairs, spill, scnt, E, gpb);
    bsum_kernel<<<NB2, BTHR, 0, stream>>>(brun, pairs, x, out, N, gpb);
    spill_kernel<<<64, 256, 0, stream>>>(spill, scnt, x, out);
}